// Round 10
// baseline (246.125 us; speedup 1.0000x reference)
//
#include <hip/hip_runtime.h>
#include <math.h>

typedef __bf16 bf16x8 __attribute__((ext_vector_type(8)));
typedef float f32x4 __attribute__((ext_vector_type(4)));

// ---------- helpers ----------

__device__ __forceinline__ unsigned short f2bf(float f) {
    unsigned int u = __float_as_uint(f);
    u += 0x7FFFu + ((u >> 16) & 1u);   // round-to-nearest-even
    return (unsigned short)(u >> 16);
}

// fast logcosh via HW v_exp/v_log (TRANS pipe). abs err ~1e-6/elem, budget 0.02.
__device__ __forceinline__ float logcosh_fast(float v) {
    float a = fabsf(v);
    float t = __expf(-2.0f * a);
    return a + (__logf(1.0f + t) - 0.6931471805599453f);
}

// DPP row_shr add; after shr 1,2,4,8 lane 15 of each 16-lane row holds row sum.
template <int CTRL>
__device__ __forceinline__ float dppadd(float x) {
    int y = __builtin_amdgcn_update_dpp(0, __float_as_int(x), CTRL, 0xf, 0xf, true);
    return x + __int_as_float(y);
}

__device__ __forceinline__ void gload_lds16(const void* g, void* l) {
    __builtin_amdgcn_global_load_lds(
        (__attribute__((address_space(1))) void*)(void*)g,
        (__attribute__((address_space(3))) void*)l, 16, 0, 0);
}

#define SBAR()  __builtin_amdgcn_s_barrier()
#define SCHED() __builtin_amdgcn_sched_barrier(0)

// ---------- kernel 1: invert permutations ----------
__global__ __launch_bounds__(256) void k_invert(const int* __restrict__ perms,
                                                int* __restrict__ inv) {
    int t = blockIdx.x * 256 + threadIdx.x;
    int g = t >> 10, n = t & 1023;
    inv[(g << 10) + perms[t]] = n;
}

// ---------- kernel 2: bT[j][k] = bf16(W[inv[g][k]][f]), j = g*16+f ----------
__global__ __launch_bounds__(256) void k_build_bt(const float* __restrict__ W,
                                                  const int* __restrict__ inv,
                                                  unsigned short* __restrict__ bT) {
    int j = blockIdx.x;
    int g = j >> 4, f = j & 15;
    const int* invg = inv + (g << 10);
    size_t rowbase = (size_t)j << 10;
#pragma unroll
    for (int i = 0; i < 4; ++i) {
        int k = (i << 8) + threadIdx.x;
        int n = invg[k];
        bT[rowbase + k] = f2bf(W[(n << 4) + f]);
    }
}

// ---------- kernel 3: x -> bf16, out[row] = v_bias * sum(x[row]) ----------
__global__ __launch_bounds__(256) void k_convert(const float* __restrict__ x,
                                                 const float* __restrict__ vb,
                                                 unsigned short* __restrict__ xb,
                                                 float* __restrict__ out) {
    int row = blockIdx.x, tid = threadIdx.x;
    size_t base = ((size_t)row << 10) + (tid << 2);
    float4 v = *reinterpret_cast<const float4*>(x + base);
    ushort4 h;
    h.x = f2bf(v.x); h.y = f2bf(v.y); h.z = f2bf(v.z); h.w = f2bf(v.w);
    *reinterpret_cast<ushort4*>(xb + base) = h;
    float s = v.x + v.y + v.z + v.w;
#pragma unroll
    for (int off = 32; off > 0; off >>= 1) s += __shfl_down(s, off);
    __shared__ float ls[4];
    if ((tid & 63) == 0) ls[tid >> 6] = s;
    __syncthreads();
    if (tid == 0) out[row] = vb[0] * (ls[0] + ls[1] + ls[2] + ls[3]);
}

// ---------- kernel 4: 256x256 GEMM. A in LDS; B DIRECT global->VGPR (L2-resident).
// 8 waves (2m x 4n), per-wave 128x64, acc[8][4]. 16 K-tiles BK=64.
// Per tile (m-walk, 2 barriers):
//   start: ds_read aF frags 0,1 (4)
//   m=0..5: { ds_read frag m+2 (2); lgkm(4) -> frag m ready; 8 MFMA m }
//   lgkm(0); SBAR                      // all waves' A(t)-reads drained
//   ph6: stage A(t+2)->this buf (4 gload_lds); 8 MFMA m=6
//   ph7: 8 MFMA m=7; issue B(t+2)->bFc regs (after last bFc use); vmcnt(12); SBAR
// vmcnt(12): outstanding = A(t+1)4,B(t+1)8 (oldest) + A(t+2)4,B(t+2)8 -> t+1 ready.
// LDS/tile = A reads 128KB + A stage 32KB = 160KB < MFMA floor. B: 64KB/tile from
// L2 (panel 512KB, resident via cbx-slowest swizzle; 64B-line coalesced).

#define MFMA_M(MM, AFR)                                                          \
    _Pragma("unroll") for (int kk_ = 0; kk_ < 2; ++kk_)                          \
    _Pragma("unroll") for (int n_ = 0; n_ < 4; ++n_)                             \
        acc[MM][n_] = __builtin_amdgcn_mfma_f32_16x16x32_bf16(                   \
            AFR[kk_], bF[n_][kk_], acc[MM][n_], 0, 0, 0);

// stage instr i (of 4) for one 256x64 tile: 512 chunks, thread voff precomputed
__device__ __forceinline__ void stage_i(unsigned short* dst, const unsigned short* src,
                                        int voff, int i, int wv) {
    gload_lds16(src + voff, dst + (((i << 9) + wv * 64) << 3));
}

template <bool STA, bool LDB, int VM>
__device__ __forceinline__ void tile_mw(
    const unsigned short* Ap,        // LDS A buf (tile t); also dst for A(t+2)
    unsigned short* Adst,
    const unsigned short* xsrc,      // global A(t+2) src
    const unsigned short* bcol,      // per-lane B base (j-column of bT)
    int ktN,                         // shorts offset for B(t+2) loads
    bf16x8 (&bF)[4][2],              // bFc: used this tile, refilled with B(t+2)
    f32x4 (&acc)[8][4],
    const int (&vs)[4], int aRow, int po0, int po1, int wv) {
    bf16x8 aF[4][2];

    // tile start: frags 0,1
#pragma unroll
    for (int m = 0; m < 2; ++m) {
        aF[m][0] = *reinterpret_cast<const bf16x8*>(Ap + aRow + po0 + m * 1024);
        aF[m][1] = *reinterpret_cast<const bf16x8*>(Ap + aRow + po1 + m * 1024);
    }
    SCHED();
    // phases 0..5: read frag m+2 into ring slot, lgkm(4) -> frag m ready, 8 MFMA
#pragma unroll
    for (int m = 0; m < 6; ++m) {
        aF[(m + 2) & 3][0] = *reinterpret_cast<const bf16x8*>(Ap + aRow + po0 + (m + 2) * 1024);
        aF[(m + 2) & 3][1] = *reinterpret_cast<const bf16x8*>(Ap + aRow + po1 + (m + 2) * 1024);
        SCHED();
        asm volatile("s_waitcnt lgkmcnt(4)" ::: "memory");
        SCHED();
        __builtin_amdgcn_s_setprio(1);
        MFMA_M(m, aF[m & 3])
        __builtin_amdgcn_s_setprio(0);
        SCHED();
    }
    asm volatile("s_waitcnt lgkmcnt(0)" ::: "memory");
    SCHED();
    SBAR();   // all waves' A(t)-reads drained -> staging into Ap is safe

    // phase 6: stage A(t+2); MFMA m=6
    if (STA) {
#pragma unroll
        for (int i = 0; i < 4; ++i) stage_i(Adst, xsrc, vs[i], i, wv);
    }
    SCHED();
    __builtin_amdgcn_s_setprio(1);
    MFMA_M(6, aF[2])
    __builtin_amdgcn_s_setprio(0);
    SCHED();

    // phase 7: MFMA m=7; then refill bF with B(t+2) (after last use); vmcnt; SBAR
    __builtin_amdgcn_s_setprio(1);
    MFMA_M(7, aF[3])
    __builtin_amdgcn_s_setprio(0);
    SCHED();
    if (LDB) {
#pragma unroll
        for (int n = 0; n < 4; ++n) {
            bF[n][0] = *reinterpret_cast<const bf16x8*>(bcol + ktN + n * 16384);
            bF[n][1] = *reinterpret_cast<const bf16x8*>(bcol + ktN + n * 16384 + 32);
        }
    }
    SCHED();
    if (VM == 12)     { asm volatile("s_waitcnt vmcnt(12)" ::: "memory"); }
    else if (VM == 0) { asm volatile("s_waitcnt vmcnt(0)" ::: "memory"); }
    SCHED();
    SBAR();
}

__global__ __launch_bounds__(512, 2) void k_gemm(const unsigned short* __restrict__ xb,
                                                 const unsigned short* __restrict__ bT,
                                                 const float* __restrict__ bias,
                                                 float* __restrict__ partial, int B) {
    __shared__ unsigned short As[2][256 * 64];

    const int tid = threadIdx.x;
    const int lane = tid & 63;
    const int wv = tid >> 6;           // 0..7
    const int wm = wv >> 2;            // 0..1  (M half)
    const int wn = wv & 3;             // 0..3  (N quarter)
    const int lr = lane & 15;
    const int lk = lane >> 4;

    // XCD-bijective swizzle; row-block varies FASTEST so each XCD keeps one
    // B panel (512KB) L2-resident across a 64-block run.
    const int fid = blockIdx.y * gridDim.x + blockIdx.x;   // nwg = 1024
    const int cpx = (gridDim.x * gridDim.y) >> 3;          // 128
    const int swz = (fid & 7) * cpx + (fid >> 3);
    const int rowb = swz & 63;
    const int cbx = swz >> 6;          // col block (0..15)
    const int row0 = rowb << 8;
    const int j0 = cbx << 8;

    const unsigned short* xbase = xb + ((size_t)row0 << 10);
    // per-lane B column base: j = j0 + wn*64 + lr (+n*16), k base = lk*8
    const unsigned short* bcol = bT + (((size_t)(j0 + wn * 64 + lr)) << 10) + lk * 8;

    // hoisted per-wave LDS read bases (short units); +m*1024 imm offsets
    const int aRow = (wm * 128 + lr) * 64;
    const int po0 = (lk ^ (lr & 7)) * 8;
    const int po1 = ((4 + lk) ^ (lr & 7)) * 8;

    // per-thread stage source voffsets (shorts), instr i covers chunks i*512+tid
    int vs[4];
#pragma unroll
    for (int i = 0; i < 4; ++i) {
        int cc = (i << 9) + tid;
        int r = cc >> 3;
        int cs = (cc & 7) ^ (r & 7);
        vs[i] = (r << 10) + (cs << 3);
    }

    f32x4 acc[8][4];
#pragma unroll
    for (int m = 0; m < 8; ++m)
#pragma unroll
        for (int n = 0; n < 4; ++n)
            acc[m][n] = {0.f, 0.f, 0.f, 0.f};

    bf16x8 bF0[4][2], bF1[4][2];

    // ---- prologue: A(0) stage, B(0) regs, A(1) stage, B(1) regs; vmcnt(12) ----
#pragma unroll
    for (int i = 0; i < 4; ++i) stage_i(&As[0][0], xbase, vs[i], i, wv);
#pragma unroll
    for (int n = 0; n < 4; ++n) {
        bF0[n][0] = *reinterpret_cast<const bf16x8*>(bcol + n * 16384);
        bF0[n][1] = *reinterpret_cast<const bf16x8*>(bcol + n * 16384 + 32);
    }
#pragma unroll
    for (int i = 0; i < 4; ++i) stage_i(&As[1][0], xbase + 64, vs[i], i, wv);
#pragma unroll
    for (int n = 0; n < 4; ++n) {
        bF1[n][0] = *reinterpret_cast<const bf16x8*>(bcol + 64 + n * 16384);
        bF1[n][1] = *reinterpret_cast<const bf16x8*>(bcol + 64 + n * 16384 + 32);
    }
    asm volatile("s_waitcnt vmcnt(12)" ::: "memory");   // A(0), B(0) landed
    SCHED();
    SBAR();

    // ---- main loop: tiles 0..13 steady; 14,15 tail ----
    for (int tt = 0; tt < 7; ++tt) {
        const int t0 = tt * 2;
        // even tile: buf As0, frags bF0; stage A(t+2)->As0; load B(t+2)->bF0
        tile_mw<true, true, 12>(&As[0][0], &As[0][0], xbase + ((t0 + 2) << 6),
                                bcol, (t0 + 2) << 6,
                                bF0, acc, vs, aRow, po0, po1, wv);
        // odd tile: buf As1, frags bF1
        tile_mw<true, true, 12>(&As[1][0], &As[1][0], xbase + ((t0 + 3) << 6),
                                bcol, (t0 + 3) << 6,
                                bF1, acc, vs, aRow, po0, po1, wv);
    }
    // t=14: no stage/load; drain everything for t=15
    tile_mw<false, false, 0>(&As[0][0], &As[0][0], xbase, bcol, 0,
                             bF0, acc, vs, aRow, po0, po1, wv);
    // t=15: nothing outstanding
    tile_mw<false, false, -1>(&As[1][0], &As[1][0], xbase, bcol, 0,
                              bF1, acc, vs, aRow, po0, po1, wv);

    // ---- epilogue: fast logcosh + DPP row-reduce; reuse As as scratch ----
    float* rowsum = (float*)&As[0][0];   // [4][256]
    const float bv = bias[lr];           // C col % 16 == lane&15
#pragma unroll
    for (int m = 0; m < 8; ++m) {
#pragma unroll
        for (int r = 0; r < 4; ++r) {
            float s = 0.f;
#pragma unroll
            for (int n = 0; n < 4; ++n) s += logcosh_fast(acc[m][n][r] + bv);
            s = dppadd<0x111>(s);
            s = dppadd<0x112>(s);
            s = dppadd<0x114>(s);
            s = dppadd<0x118>(s);
            if (lr == 15)
                rowsum[wn * 256 + wm * 128 + m * 16 + lk * 4 + r] = s;
        }
    }
    __syncthreads();
    if (tid < 256) {
        float s = rowsum[tid] + rowsum[256 + tid] + rowsum[512 + tid] + rowsum[768 + tid];
        partial[(size_t)cbx * B + row0 + tid] = s;
    }
}

// ---------- kernel 5: out[b] += sum_cb partial[cb][b] ----------
__global__ __launch_bounds__(256) void k_final(const float* __restrict__ partial,
                                               float* __restrict__ out, int ncb, int B) {
    int b = blockIdx.x * 256 + threadIdx.x;
    float s = out[b];
    for (int c = 0; c < ncb; ++c) s += partial[(size_t)c * B + b];
    out[b] = s;
}

// ---------- launch ----------
extern "C" void kernel_launch(void* const* d_in, const int* in_sizes, int n_in,
                              void* d_out, int out_size, void* d_ws, size_t ws_size,
                              hipStream_t stream) {
    const float* x      = (const float*)d_in[0];  // [B,1024]
    const float* W      = (const float*)d_in[1];  // [1024,16]
    const float* bias   = (const float*)d_in[2];  // [16]
    const float* v_bias = (const float*)d_in[3];  // [1]
    const int*   perms  = (const int*)d_in[4];    // [G,1024]
    float* out = (float*)d_out;

    const int N  = 1024;
    const int B  = in_sizes[0] / N;   // 16384
    const int G  = in_sizes[4] / N;   // 256
    const int GF = G * 16;            // 4096
    const int NCB = GF / 256;         // 16 col blocks

    char* w = (char*)d_ws;
    unsigned short* xb = (unsigned short*)w;                           // B*N*2   = 32 MB
    unsigned short* bT = (unsigned short*)(w + (size_t)B * N * 2);     // GF*N*2  = 8 MB
    int* inv = (int*)(w + (size_t)B * N * 2 + (size_t)GF * N * 2);     // G*N*4   = 1 MB
    float* partial = (float*)(w + (size_t)B * N * 2 + (size_t)GF * N * 2
                              + (size_t)G * N * 4);                    // NCB*B*4 = 1 MB

    k_invert<<<G * N / 256, 256, 0, stream>>>(perms, inv);
    k_build_bt<<<GF, 256, 0, stream>>>(W, inv, bT);
    k_convert<<<B, 256, 0, stream>>>(x, v_bias, xb, out);
    k_gemm<<<dim3(NCB, B / 256), 512, 0, stream>>>(xb, bT, bias, partial, B);
    k_final<<<B / 256, 256, 0, stream>>>(partial, out, NCB, B);
}

// Round 11
// 221.841 us; speedup vs baseline: 1.1095x; 1.1095x over previous
//
#include <hip/hip_runtime.h>
#include <math.h>

typedef __bf16 bf16x8 __attribute__((ext_vector_type(8)));
typedef float f32x4 __attribute__((ext_vector_type(4)));

// ---------- helpers ----------

__device__ __forceinline__ unsigned short f2bf(float f) {
    unsigned int u = __float_as_uint(f);
    u += 0x7FFFu + ((u >> 16) & 1u);   // round-to-nearest-even
    return (unsigned short)(u >> 16);
}

// fast logcosh via HW v_exp/v_log (TRANS pipe). abs err ~1e-6/elem, budget 0.02.
__device__ __forceinline__ float logcosh_fast(float v) {
    float a = fabsf(v);
    float t = __expf(-2.0f * a);
    return a + (__logf(1.0f + t) - 0.6931471805599453f);
}

// DPP row_shr add; after shr 1,2,4,8 lane 15 of each 16-lane row holds row sum.
template <int CTRL>
__device__ __forceinline__ float dppadd(float x) {
    int y = __builtin_amdgcn_update_dpp(0, __float_as_int(x), CTRL, 0xf, 0xf, true);
    return x + __int_as_float(y);
}

__device__ __forceinline__ void gload_lds16(const void* g, void* l) {
    __builtin_amdgcn_global_load_lds(
        (__attribute__((address_space(1))) void*)(void*)g,
        (__attribute__((address_space(3))) void*)l, 16, 0, 0);
}

#define SBAR()  __builtin_amdgcn_s_barrier()
#define SCHED() __builtin_amdgcn_sched_barrier(0)

// ---------- kernel 1: invert permutations ----------
__global__ __launch_bounds__(256) void k_invert(const int* __restrict__ perms,
                                                int* __restrict__ inv) {
    int t = blockIdx.x * 256 + threadIdx.x;
    int g = t >> 10, n = t & 1023;
    inv[(g << 10) + perms[t]] = n;
}

// ---------- kernel 2: bT[j][k] = bf16(W[inv[g][k]][f]), j = g*16+f ----------
__global__ __launch_bounds__(256) void k_build_bt(const float* __restrict__ W,
                                                  const int* __restrict__ inv,
                                                  unsigned short* __restrict__ bT) {
    int j = blockIdx.x;
    int g = j >> 4, f = j & 15;
    const int* invg = inv + (g << 10);
    size_t rowbase = (size_t)j << 10;
#pragma unroll
    for (int i = 0; i < 4; ++i) {
        int k = (i << 8) + threadIdx.x;
        int n = invg[k];
        bT[rowbase + k] = f2bf(W[(n << 4) + f]);
    }
}

// ---------- kernel 3: x -> bf16, out[row] = v_bias * sum(x[row]) ----------
__global__ __launch_bounds__(256) void k_convert(const float* __restrict__ x,
                                                 const float* __restrict__ vb,
                                                 unsigned short* __restrict__ xb,
                                                 float* __restrict__ out) {
    int row = blockIdx.x, tid = threadIdx.x;
    size_t base = ((size_t)row << 10) + (tid << 2);
    float4 v = *reinterpret_cast<const float4*>(x + base);
    ushort4 h;
    h.x = f2bf(v.x); h.y = f2bf(v.y); h.z = f2bf(v.z); h.w = f2bf(v.w);
    *reinterpret_cast<ushort4*>(xb + base) = h;
    float s = v.x + v.y + v.z + v.w;
#pragma unroll
    for (int off = 32; off > 0; off >>= 1) s += __shfl_down(s, off);
    __shared__ float ls[4];
    if ((tid & 63) == 0) ls[tid >> 6] = s;
    __syncthreads();
    if (tid == 0) out[row] = vb[0] * (ls[0] + ls[1] + ls[2] + ls[3]);
}

// ---------- kernel 4: 128x128 GEMM, A+B in LDS, m-walk schedule, 2 blocks/CU ----
// 4 waves (2m x 2n), per-wave 64x64, acc[4][4]. 16 K-tiles BK=64. LDS 64KB ->
// TWO blocks co-resident per CU: cross-block MFMA/LDS pipe overlap (m114)
// converts the sum-of-floors (1-block convoy) toward max-of-floors.
// Per tile (2 barriers): 12 ds_reads up front (bF x8, aF0-1), m-phases with
// counted lgkm(4/4/2/0), SBAR (all reads of buf p drained), stage A+B(t+2)
// (8 gload_lds), vmcnt(8) [t+1's 8 stages = oldest outstanding], SBAR.

#define MFMA_M(MM)                                                               \
    _Pragma("unroll") for (int kk_ = 0; kk_ < 2; ++kk_)                          \
    _Pragma("unroll") for (int n_ = 0; n_ < 4; ++n_)                             \
        acc[MM][n_] = __builtin_amdgcn_mfma_f32_16x16x32_bf16(                   \
            aF[MM][kk_], bF[n_][kk_], acc[MM][n_], 0, 0, 0);

// stage instr i (of 4) for one 128x64 tile: 256 chunks of 16B, 256 threads
__device__ __forceinline__ void stage128(unsigned short* dst, const unsigned short* src,
                                         int voff, int i, int wv) {
    gload_lds16(src + voff, dst + (((i << 8) + (wv << 6)) << 3));
}

template <bool ST, int VM>
__device__ __forceinline__ void tile128(
    const unsigned short* Ap, const unsigned short* Bp,   // read bufs (tile t)
    unsigned short* Adst, unsigned short* Bdst,           // same bufs (t+2 dst)
    const unsigned short* xsrc, const unsigned short* bsrc,
    f32x4 (&acc)[4][4], const int (&vs)[4],
    int aRow, int bRow, int po0, int po1, int wv) {
    bf16x8 aF[4][2], bF[4][2];

    // front: 8 bF reads then aF0, aF1 (issue order = ledger order)
#pragma unroll
    for (int n = 0; n < 4; ++n) {
        bF[n][0] = *reinterpret_cast<const bf16x8*>(Bp + bRow + po0 + n * 1024);
        bF[n][1] = *reinterpret_cast<const bf16x8*>(Bp + bRow + po1 + n * 1024);
    }
#pragma unroll
    for (int m = 0; m < 2; ++m) {
        aF[m][0] = *reinterpret_cast<const bf16x8*>(Ap + aRow + po0 + m * 1024);
        aF[m][1] = *reinterpret_cast<const bf16x8*>(Ap + aRow + po1 + m * 1024);
    }
    SCHED();
    // m=0: issue aF2; lgkm(4) -> bF+aF0 done
    aF[2][0] = *reinterpret_cast<const bf16x8*>(Ap + aRow + po0 + 2 * 1024);
    aF[2][1] = *reinterpret_cast<const bf16x8*>(Ap + aRow + po1 + 2 * 1024);
    SCHED();
    asm volatile("s_waitcnt lgkmcnt(4)" ::: "memory");
    SCHED();
    __builtin_amdgcn_s_setprio(1);
    MFMA_M(0)
    __builtin_amdgcn_s_setprio(0);
    SCHED();
    // m=1: issue aF3; lgkm(4) -> aF1 done
    aF[3][0] = *reinterpret_cast<const bf16x8*>(Ap + aRow + po0 + 3 * 1024);
    aF[3][1] = *reinterpret_cast<const bf16x8*>(Ap + aRow + po1 + 3 * 1024);
    SCHED();
    asm volatile("s_waitcnt lgkmcnt(4)" ::: "memory");
    SCHED();
    __builtin_amdgcn_s_setprio(1);
    MFMA_M(1)
    __builtin_amdgcn_s_setprio(0);
    SCHED();
    // m=2: lgkm(2) -> aF2 done
    asm volatile("s_waitcnt lgkmcnt(2)" ::: "memory");
    SCHED();
    __builtin_amdgcn_s_setprio(1);
    MFMA_M(2)
    __builtin_amdgcn_s_setprio(0);
    SCHED();
    // m=3: lgkm(0) -> aF3 done
    asm volatile("s_waitcnt lgkmcnt(0)" ::: "memory");
    SCHED();
    __builtin_amdgcn_s_setprio(1);
    MFMA_M(3)
    __builtin_amdgcn_s_setprio(0);
    SCHED();
    SBAR();   // all waves' reads of buf p drained -> stages into p safe

    if (ST) {
#pragma unroll
        for (int i = 0; i < 4; ++i) stage128(Adst, xsrc, vs[i], i, wv);
#pragma unroll
        for (int i = 0; i < 4; ++i) stage128(Bdst, bsrc, vs[i], i, wv);
    }
    SCHED();
    if (VM == 8)      { asm volatile("s_waitcnt vmcnt(8)" ::: "memory"); }
    else if (VM == 0) { asm volatile("s_waitcnt vmcnt(0)" ::: "memory"); }
    SCHED();
    SBAR();   // buf q (tile t+1) ready
}

__global__ __launch_bounds__(256, 4) void k_gemm(const unsigned short* __restrict__ xb,
                                                 const unsigned short* __restrict__ bT,
                                                 const float* __restrict__ bias,
                                                 float* __restrict__ partial, int B) {
    __shared__ unsigned short As[2][128 * 64];
    __shared__ unsigned short Bs[2][128 * 64];

    const int tid = threadIdx.x;
    const int lane = tid & 63;
    const int wv = tid >> 6;           // 0..3
    const int wm = wv >> 1;            // 0..1  (M half)
    const int wn = wv & 1;             // 0..1  (N half)
    const int lr = lane & 15;
    const int lk = lane >> 4;

    // XCD-bijective swizzle, col-block slowest: each XCD's concurrent blocks
    // share one B panel (256KB, L2-resident); A streams.
    const int fid = blockIdx.y * gridDim.x + blockIdx.x;   // nwg = 4096
    const int cpx = (gridDim.x * gridDim.y) >> 3;          // 512
    const int swz = (fid & 7) * cpx + (fid >> 3);
    const int rowb = swz & 127;
    const int cbx = swz >> 7;          // col block (0..31)
    const int row0 = rowb << 7;
    const int j0 = cbx << 7;

    const unsigned short* xbase = xb + ((size_t)row0 << 10);
    const unsigned short* bbase = bT + ((size_t)j0 << 10);

    // per-wave LDS read bases (short units); +m*1024 / +n*1024 imm offsets
    const int aRow = (wm * 64 + lr) * 64;
    const int bRow = (wn * 64 + lr) * 64;
    const int po0 = (lk ^ (lr & 7)) * 8;
    const int po1 = ((4 + lk) ^ (lr & 7)) * 8;

    // per-thread stage source voffsets (shorts); instr i covers chunks i*256+tid
    int vs[4];
#pragma unroll
    for (int i = 0; i < 4; ++i) {
        int cc = (i << 8) + tid;
        int r = cc >> 3;
        int cs = (cc & 7) ^ (r & 7);
        vs[i] = (r << 10) + (cs << 3);
    }

    f32x4 acc[4][4];
#pragma unroll
    for (int m = 0; m < 4; ++m)
#pragma unroll
        for (int n = 0; n < 4; ++n)
            acc[m][n] = {0.f, 0.f, 0.f, 0.f};

    // ---- prologue: stage tile0 (A,B) + tile1 (A,B); wait tile0; SBAR ----
#pragma unroll
    for (int i = 0; i < 4; ++i) stage128(&As[0][0], xbase, vs[i], i, wv);
#pragma unroll
    for (int i = 0; i < 4; ++i) stage128(&Bs[0][0], bbase, vs[i], i, wv);
#pragma unroll
    for (int i = 0; i < 4; ++i) stage128(&As[1][0], xbase + 64, vs[i], i, wv);
#pragma unroll
    for (int i = 0; i < 4; ++i) stage128(&Bs[1][0], bbase + 64, vs[i], i, wv);
    asm volatile("s_waitcnt vmcnt(8)" ::: "memory");   // tile0 landed
    SCHED();
    SBAR();

    // ---- main loop: tiles 0..13 steady (stage t+2, vmcnt(8)); 14,15 tail ----
    for (int tt = 0; tt < 7; ++tt) {
        const int t0 = tt * 2;
        tile128<true, 8>(&As[0][0], &Bs[0][0], &As[0][0], &Bs[0][0],
                         xbase + ((t0 + 2) << 6), bbase + ((t0 + 2) << 6),
                         acc, vs, aRow, bRow, po0, po1, wv);
        tile128<true, 8>(&As[1][0], &Bs[1][0], &As[1][0], &Bs[1][0],
                         xbase + ((t0 + 3) << 6), bbase + ((t0 + 3) << 6),
                         acc, vs, aRow, bRow, po0, po1, wv);
    }
    tile128<false, 0>(&As[0][0], &Bs[0][0], &As[0][0], &Bs[0][0],
                      xbase, bbase, acc, vs, aRow, bRow, po0, po1, wv);
    tile128<false, -1>(&As[1][0], &Bs[1][0], &As[1][0], &Bs[1][0],
                       xbase, bbase, acc, vs, aRow, bRow, po0, po1, wv);

    // ---- epilogue: fast logcosh + DPP row-reduce; combine wn halves in LDS ----
    float* rowsum = (float*)&As[0][0];   // [2][128]
    const float bv = bias[lr];           // C col % 16 == lane&15
#pragma unroll
    for (int m = 0; m < 4; ++m) {
#pragma unroll
        for (int r = 0; r < 4; ++r) {
            float s = 0.f;
#pragma unroll
            for (int n = 0; n < 4; ++n) s += logcosh_fast(acc[m][n][r] + bv);
            s = dppadd<0x111>(s);
            s = dppadd<0x112>(s);
            s = dppadd<0x114>(s);
            s = dppadd<0x118>(s);
            if (lr == 15)
                rowsum[wn * 128 + wm * 64 + m * 16 + lk * 4 + r] = s;
        }
    }
    __syncthreads();
    if (tid < 128)
        partial[(size_t)cbx * B + row0 + tid] = rowsum[tid] + rowsum[128 + tid];
}

// ---------- kernel 5: out[b] += sum_cb partial[cb][b] ----------
__global__ __launch_bounds__(256) void k_final(const float* __restrict__ partial,
                                               float* __restrict__ out, int ncb, int B) {
    int b = blockIdx.x * 256 + threadIdx.x;
    float s = out[b];
    for (int c = 0; c < ncb; ++c) s += partial[(size_t)c * B + b];
    out[b] = s;
}

// ---------- launch ----------
extern "C" void kernel_launch(void* const* d_in, const int* in_sizes, int n_in,
                              void* d_out, int out_size, void* d_ws, size_t ws_size,
                              hipStream_t stream) {
    const float* x      = (const float*)d_in[0];  // [B,1024]
    const float* W      = (const float*)d_in[1];  // [1024,16]
    const float* bias   = (const float*)d_in[2];  // [16]
    const float* v_bias = (const float*)d_in[3];  // [1]
    const int*   perms  = (const int*)d_in[4];    // [G,1024]
    float* out = (float*)d_out;

    const int N  = 1024;
    const int B  = in_sizes[0] / N;   // 16384
    const int G  = in_sizes[4] / N;   // 256
    const int GF = G * 16;            // 4096
    const int NCB = GF / 128;         // 32 col blocks

    char* w = (char*)d_ws;
    unsigned short* xb = (unsigned short*)w;                           // B*N*2   = 32 MB
    unsigned short* bT = (unsigned short*)(w + (size_t)B * N * 2);     // GF*N*2  = 8 MB
    int* inv = (int*)(w + (size_t)B * N * 2 + (size_t)GF * N * 2);     // G*N*4   = 1 MB
    float* partial = (float*)(w + (size_t)B * N * 2 + (size_t)GF * N * 2
                              + (size_t)G * N * 4);                    // NCB*B*4 = 2 MB

    k_invert<<<G * N / 256, 256, 0, stream>>>(perms, inv);
    k_build_bt<<<GF, 256, 0, stream>>>(W, inv, bT);
    k_convert<<<B, 256, 0, stream>>>(x, v_bias, xb, out);
    k_gemm<<<dim3(NCB, B / 128), 256, 0, stream>>>(xb, bT, bias, partial, B);
    k_final<<<B / 256, 256, 0, stream>>>(partial, out, NCB, B);
}